// Round 20
// baseline (116.881 us; speedup 1.0000x reference)
//
#include <hip/hip_runtime.h>

// VQ-VAE forward: N=131072 rows (D=64), K=512 codes.
// Outputs flat: [loss(1) | quantized_st(8388608, NCHW) | perplexity(1) | encodings(131072x512)]
//
// R20: generation-pipelined vq_all. R19 (101us) is phase-lockstep: grid 512 = all blocks
// resident, whole machine computes (write pipe idle) then drains stores (VALU idle).
// Change: 1 group/block, grid 2048 -> 4 generations at 2 blocks/CU. A retiring block's
// stores (41 store-instrs/thread < vmcnt cap 63 -> issue fully, retire at s_endpgm) drain
// WHILE the next generation's blocks load/compute in the freed slot. Store stream becomes
// continuous. Phase order (all loads before all stores), store patterns, math, tie-breaks
// byte-identical to R19. lossPart: 2048 entries, fin sums 4/thread.

#define OFF_Q    1
#define OFF_PERP 8388609
#define OFF_ENC  8388610

typedef float accf4 __attribute__((ext_vector_type(4)));
typedef short bfrag8 __attribute__((ext_vector_type(8)));

__device__ __forceinline__ unsigned short f2bf(float f) {
    union { float f; unsigned u; } v; v.f = f;
    unsigned r = v.u + 0x7FFFu + ((v.u >> 16) & 1u);   // RNE
    return (unsigned short)(r >> 16);
}

__device__ __forceinline__ void lds_barrier() {
    asm volatile("s_waitcnt lgkmcnt(0)" ::: "memory");
    __builtin_amdgcn_s_barrier();
    asm volatile("" ::: "memory");
}

__global__ __launch_bounds__(512) void vq_prep(const float* __restrict__ emb,
                                               float* __restrict__ Bk,
                                               unsigned* __restrict__ counts) {
    int k = threadIdx.x;
    const float4* e4 = reinterpret_cast<const float4*>(emb) + k * 16;
    float s = 0.f;
    #pragma unroll
    for (int i = 0; i < 16; ++i) {
        float4 v = e4[i];
        s += v.x * v.x + v.y * v.y + v.z * v.z + v.w * v.w;
    }
    Bk[k] = s;
    counts[k] = 0u;
}

// ---- vq_all: one row-group per block; loads-before-stores; 3 barriers ----
__global__ __launch_bounds__(512, 4) void vq_all(const float* __restrict__ in,
                                                 const float* __restrict__ emb,
                                                 const float* __restrict__ Bk,
                                                 int* __restrict__ idx,
                                                 float* __restrict__ lossPart,
                                                 float* __restrict__ out) {
    __shared__ __align__(16) unsigned short xB[64][72];   // 9216B
    __shared__ float sdw[8][64];                          // 2048B
    __shared__ int   skw[8][64];                          // 2048B
    __shared__ int   fkL[64];                             //  256B
    __shared__ float lossW[8];

    const int tid  = (int)threadIdx.x;
    const int lane = tid & 63;
    const int v    = __builtin_amdgcn_readfirstlane(tid >> 6);  // wave 0..7
    const int q    = lane >> 4;
    const int cidx = lane & 15;

    const int gab = (int)blockIdx.x;             // row-group 0..2047 = b*64+h
    const size_t rowBase = (size_t)(gab >> 6) * 262144 + (size_t)(gab & 63) * 64 + (size_t)lane;

    // E A-fragments (loads; L2-hot) — layout R10 HW-verified.
    bfrag8 efr[4][2];
    #pragma unroll
    for (int tn = 0; tn < 4; ++tn) {
        #pragma unroll
        for (int ks = 0; ks < 2; ++ks) {
            const float* ep = emb + (size_t)(v * 64 + tn * 16 + cidx) * 64 + ks * 32 + q * 8;
            float4 e0 = *reinterpret_cast<const float4*>(ep);
            float4 e1 = *reinterpret_cast<const float4*>(ep + 4);
            bfrag8 b;
            b[0] = (short)f2bf(e0.x); b[1] = (short)f2bf(e0.y);
            b[2] = (short)f2bf(e0.z); b[3] = (short)f2bf(e0.w);
            b[4] = (short)f2bf(e1.x); b[5] = (short)f2bf(e1.y);
            b[6] = (short)f2bf(e1.z); b[7] = (short)f2bf(e1.w);
            efr[tn][ks] = b;
        }
    }
    float4 Bn[4];
    #pragma unroll
    for (int tn = 0; tn < 4; ++tn)
        Bn[tn] = *reinterpret_cast<const float4*>(&Bk[v * 64 + tn * 16 + q * 4]);
    const int kbaseLane = v * 64 + q * 4;

    // ---- phase 1: load x (8 coalesced loads/thread), pack -> LDS ----
    float lacc = 0.f;
    {
        bfrag8 xpk;
        #pragma unroll
        for (int cc = 0; cc < 8; ++cc) {
            const float val = in[rowBase + (size_t)(v * 8 + cc) * 4096];
            lacc += val * val;
            xpk[cc] = (short)f2bf(val);
        }
        *reinterpret_cast<bfrag8*>(&xB[lane][v * 8]) = xpk;
    }
    lds_barrier();   // b1: staged

    // ---- phase 2: MFMA + argmin (LDS-only traffic) ----
    #pragma unroll
    for (int rt = 0; rt < 4; ++rt) {
        const bfrag8 x0 = *reinterpret_cast<const bfrag8*>(&xB[rt * 16 + cidx][q * 8]);
        const bfrag8 x1 = *reinterpret_cast<const bfrag8*>(&xB[rt * 16 + cidx][32 + q * 8]);
        accf4 acc[4];
        #pragma unroll
        for (int tn = 0; tn < 4; ++tn) {
            acc[tn] = (accf4){0.f, 0.f, 0.f, 0.f};
            acc[tn] = __builtin_amdgcn_mfma_f32_16x16x32_bf16(efr[tn][0], x0, acc[tn], 0, 0, 0);
            acc[tn] = __builtin_amdgcn_mfma_f32_16x16x32_bf16(efr[tn][1], x1, acc[tn], 0, 0, 0);
        }
        float best = 3.4e38f; int bk = kbaseLane;
        #pragma unroll
        for (int tn = 0; tn < 4; ++tn) {
            #pragma unroll
            for (int r = 0; r < 4; ++r) {
                const float Bj = (r == 0) ? Bn[tn].x : (r == 1) ? Bn[tn].y : (r == 2) ? Bn[tn].z : Bn[tn].w;
                const float d = Bj - 2.0f * acc[tn][r];
                if (d < best) { best = d; bk = kbaseLane + tn * 16 + r; }
            }
        }
        #pragma unroll
        for (int s = 16; s <= 32; s <<= 1) {
            const float od = __shfl_xor(best, s);
            const int   ok = __shfl_xor(bk, s);
            if (od < best || (od == best && ok < bk)) { best = od; bk = ok; }
        }
        if (q == 0) {
            sdw[v][rt * 16 + cidx] = best;
            skw[v][rt * 16 + cidx] = bk;
        }
    }
    lds_barrier();   // b2: per-wave argmins shared

    // every thread finalizes its own row (= lane)
    float fd = sdw[0][lane];
    int   fk = skw[0][lane];
    #pragma unroll
    for (int vv = 1; vv < 8; ++vv) {
        const float dv = sdw[vv][lane];
        const int   kv = skw[vv][lane];
        if (dv < fd) { fd = dv; fk = kv; }
    }
    if (v == 0) {
        fkL[lane] = fk;
        lacc += fd;   // per-row loss = ||x||^2 + fd
    }
    lds_barrier();   // b3: fkL visible

    // ---- phase 3: eq gather (loads; own row's fk from regs; no stores yet) ----
    const int w   = tid & 63;
    const int cq8 = tid >> 6;   // channel octet 0..7
    const float* ep = emb + (size_t)fk * 64 + cq8 * 8;
    const float4 eqa = *reinterpret_cast<const float4*>(ep);
    const float4 eqb = *reinterpret_cast<const float4*>(ep + 4);

    // ---- phase 4: ALL stores (fire-and-forget; 41/thread < vmcnt cap) ----
    if (v == 0) idx[gab * 64 + lane] = fk;
    {
        const size_t qBase = OFF_Q + (size_t)(gab >> 6) * 262144 + (size_t)(gab & 63) * 64 + (size_t)w;
        out[qBase + (size_t)(cq8 * 8 + 0) * 4096] = eqa.x;
        out[qBase + (size_t)(cq8 * 8 + 1) * 4096] = eqa.y;
        out[qBase + (size_t)(cq8 * 8 + 2) * 4096] = eqa.z;
        out[qBase + (size_t)(cq8 * 8 + 3) * 4096] = eqa.w;
        out[qBase + (size_t)(cq8 * 8 + 4) * 4096] = eqb.x;
        out[qBase + (size_t)(cq8 * 8 + 5) * 4096] = eqb.y;
        out[qBase + (size_t)(cq8 * 8 + 6) * 4096] = eqb.z;
        out[qBase + (size_t)(cq8 * 8 + 7) * 4096] = eqb.w;
    }
    {
        float2* enc2 = reinterpret_cast<float2*>(out + OFF_ENC + (size_t)gab * 32768);
        #pragma unroll 8
        for (int z = 0; z < 32; ++z) {
            const int p = z * 512 + tid;
            const int row = p >> 8;
            const int col2 = p & 255;
            const int k = fkL[row];   // LDS broadcast
            float2 val;
            val.x = ((k >> 1) == col2 && (k & 1) == 0) ? 1.0f : 0.0f;
            val.y = ((k >> 1) == col2 && (k & 1) == 1) ? 1.0f : 0.0f;
            enc2[p] = val;
        }
    }

    // loss partial (deterministic, no atomics)
    #pragma unroll
    for (int off = 32; off > 0; off >>= 1) lacc += __shfl_down(lacc, off);
    if (lane == 0) lossW[v] = lacc;
    lds_barrier();
    if (tid == 0) {
        float s = 0.f;
        #pragma unroll
        for (int i = 0; i < 8; ++i) s += lossW[i];
        lossPart[blockIdx.x] = s;
    }
}

// ---- vq_hist: counts via LDS histogram ----
__global__ __launch_bounds__(256) void vq_hist(const int* __restrict__ idx,
                                               unsigned* __restrict__ counts) {
    __shared__ unsigned h[512];
    const int tid = (int)threadIdx.x;
    h[tid] = 0u; h[tid + 256] = 0u;
    __syncthreads();
    const int base = (int)blockIdx.x * 2048;
    #pragma unroll
    for (int i = 0; i < 8; ++i)
        atomicAdd(&h[idx[base + i * 256 + tid]], 1u);
    __syncthreads();
    atomicAdd(&counts[tid], h[tid]);
    atomicAdd(&counts[tid + 256], h[tid + 256]);
}

__global__ __launch_bounds__(512) void vq_fin(const unsigned* __restrict__ counts,
                                              const float* __restrict__ lossPart,
                                              float* __restrict__ out) {
    __shared__ float red[512];
    __shared__ float lr[512];
    int k = threadIdx.x;
    float p = (float)counts[k] * (1.0f / 131072.0f);   // exact: count * 2^-17
    red[k] = p * logf(p + 1e-10f);
    lr[k] = lossPart[k] + lossPart[k + 512] + lossPart[k + 1024] + lossPart[k + 1536];
    __syncthreads();
    for (int s = 256; s > 0; s >>= 1) {
        if (k < s) { red[k] += red[k + s]; lr[k] += lr[k + s]; }
        __syncthreads();
    }
    if (k == 0) {
        out[OFF_PERP] = expf(-red[0]);
        float mf = lr[0] * (1.0f / 8388608.0f);
        out[0] = mf + 0.25f * mf;   // q_latent + 0.25 * e_latent (identical values)
    }
}

extern "C" void kernel_launch(void* const* d_in, const int* in_sizes, int n_in,
                              void* d_out, int out_size, void* d_ws, size_t ws_size,
                              hipStream_t stream) {
    const float* in  = (const float*)d_in[0];
    // d_in[1] = labels (unused by the reference forward)
    const float* emb = (const float*)d_in[2];
    float* out = (float*)d_out;

    float* Bk        = (float*)d_ws;                       // 512 f32    [0,2048)
    unsigned* counts = (unsigned*)((char*)d_ws + 2048);    // 512 u32    [2048,4096)
    float* lossPart  = (float*)((char*)d_ws + 4096);       // 2048 f32   [4096,12288)
    int* idx         = (int*)((char*)d_ws + 16384);        // 131072 i32

    vq_prep<<<1, 512, 0, stream>>>(emb, Bk, counts);
    vq_all<<<2048, 512, 0, stream>>>(in, emb, Bk, idx, lossPart, out);
    vq_hist<<<64, 256, 0, stream>>>(idx, counts);
    vq_fin<<<1, 512, 0, stream>>>(counts, lossPart, out);
}

// Round 21
// 102.209 us; speedup vs baseline: 1.1435x; 1.1435x over previous
//
#include <hip/hip_runtime.h>

// VQ-VAE forward: N=131072 rows (D=64), K=512 codes.
// Outputs flat: [loss(1) | quantized_st(8388608, NCHW) | perplexity(1) | encodings(131072x512)]
//
// R21 = R19 reverted (best: 101.4us). R20's generation pipelining regressed (117us): block
// retirement blocks on outstanding stores, so generations serialize and only the 4x E-preload
// cost remained. Final structure:
//  - vq_all: fused, loads-strictly-before-stores (R18 insight: vmcnt counts loads AND stores;
//    any load after a store force-drains the queue), 3 lgkm-only barriers (R19), 4 groups per
//    block at grid 512 (= 2 blocks/CU, all-resident), bf16 MFMA distances (R10-verified
//    fragment layouts), loss computed from winning distances (R16 algebra), no atomics (R12).
//  - vq_hist: counts via LDS histogram. vq_prep: ||e||^2. vq_fin: loss+perplexity.
// Ladder: 245 (f32 scan) -> 197 (reg-pinning) -> 185 (outer-product) -> 149 (no atomics)
// -> 122 (slim argmin) -> 119 (algebraic deletions) -> 106 (load-before-store fusion)
// -> 101.4 (barrier collapse). Probes that regressed: K-split occupancy, LDS-broadcast,
// naive fusion, 1-group blocks, barrier-free waves, generation pipelining.

#define OFF_Q    1
#define OFF_PERP 8388609
#define OFF_ENC  8388610

typedef float accf4 __attribute__((ext_vector_type(4)));
typedef short bfrag8 __attribute__((ext_vector_type(8)));

__device__ __forceinline__ unsigned short f2bf(float f) {
    union { float f; unsigned u; } v; v.f = f;
    unsigned r = v.u + 0x7FFFu + ((v.u >> 16) & 1u);   // RNE
    return (unsigned short)(r >> 16);
}

__device__ __forceinline__ void lds_barrier() {
    asm volatile("s_waitcnt lgkmcnt(0)" ::: "memory");
    __builtin_amdgcn_s_barrier();
    asm volatile("" ::: "memory");
}

__global__ __launch_bounds__(512) void vq_prep(const float* __restrict__ emb,
                                               float* __restrict__ Bk,
                                               unsigned* __restrict__ counts) {
    int k = threadIdx.x;
    const float4* e4 = reinterpret_cast<const float4*>(emb) + k * 16;
    float s = 0.f;
    #pragma unroll
    for (int i = 0; i < 16; ++i) {
        float4 v = e4[i];
        s += v.x * v.x + v.y * v.y + v.z * v.z + v.w * v.w;
    }
    Bk[k] = s;
    counts[k] = 0u;
}

// ---- vq_all: MFMA argmin + loss + idx + quantized + encodings; 3 barriers total ----
__global__ __launch_bounds__(512, 4) void vq_all(const float* __restrict__ in,
                                                 const float* __restrict__ emb,
                                                 const float* __restrict__ Bk,
                                                 int* __restrict__ idx,
                                                 float* __restrict__ lossPart,
                                                 float* __restrict__ out) {
    __shared__ __align__(16) unsigned short xB[4][64][72];  // 36864B: 4 groups staged
    __shared__ float sdw[8][256];                           // 8192B: [wave][g*64+row]
    __shared__ int   skw[8][256];                           // 8192B
    __shared__ int   fkL[4][64];                            // 1024B (enc writes)
    __shared__ float lossW[8];

    const int tid  = (int)threadIdx.x;
    const int lane = tid & 63;
    const int v    = __builtin_amdgcn_readfirstlane(tid >> 6);  // wave 0..7
    const int q    = lane >> 4;
    const int cidx = lane & 15;

    // E A-fragments (loads; L2-hot) — layout R10 HW-verified.
    bfrag8 efr[4][2];
    #pragma unroll
    for (int tn = 0; tn < 4; ++tn) {
        #pragma unroll
        for (int ks = 0; ks < 2; ++ks) {
            const float* ep = emb + (size_t)(v * 64 + tn * 16 + cidx) * 64 + ks * 32 + q * 8;
            float4 e0 = *reinterpret_cast<const float4*>(ep);
            float4 e1 = *reinterpret_cast<const float4*>(ep + 4);
            bfrag8 b;
            b[0] = (short)f2bf(e0.x); b[1] = (short)f2bf(e0.y);
            b[2] = (short)f2bf(e0.z); b[3] = (short)f2bf(e0.w);
            b[4] = (short)f2bf(e1.x); b[5] = (short)f2bf(e1.y);
            b[6] = (short)f2bf(e1.z); b[7] = (short)f2bf(e1.w);
            efr[tn][ks] = b;
        }
    }
    float4 Bn[4];
    #pragma unroll
    for (int tn = 0; tn < 4; ++tn)
        Bn[tn] = *reinterpret_cast<const float4*>(&Bk[v * 64 + tn * 16 + q * 4]);
    const int kbaseLane = v * 64 + q * 4;

    // ---- phase 1: load ALL 4 groups' x (32 coalesced loads/thread), pack -> LDS ----
    float lacc = 0.f;
    #pragma unroll
    for (int g = 0; g < 4; ++g) {
        const int gab = (int)blockIdx.x * 4 + g;
        const size_t rowBase = (size_t)(gab >> 6) * 262144 + (size_t)(gab & 63) * 64 + (size_t)lane;
        bfrag8 xpk;
        #pragma unroll
        for (int cc = 0; cc < 8; ++cc) {
            const float val = in[rowBase + (size_t)(v * 8 + cc) * 4096];
            lacc += val * val;
            xpk[cc] = (short)f2bf(val);
        }
        *reinterpret_cast<bfrag8*>(&xB[g][lane][v * 8]) = xpk;
    }
    lds_barrier();   // b1: all staged

    // ---- phase 2: MFMA + argmin, ALL groups back-to-back (no intermediate barriers) ----
    #pragma unroll 1
    for (int g = 0; g < 4; ++g) {
        #pragma unroll
        for (int rt = 0; rt < 4; ++rt) {
            const bfrag8 x0 = *reinterpret_cast<const bfrag8*>(&xB[g][rt * 16 + cidx][q * 8]);
            const bfrag8 x1 = *reinterpret_cast<const bfrag8*>(&xB[g][rt * 16 + cidx][32 + q * 8]);
            accf4 acc[4];
            #pragma unroll
            for (int tn = 0; tn < 4; ++tn) {
                acc[tn] = (accf4){0.f, 0.f, 0.f, 0.f};
                acc[tn] = __builtin_amdgcn_mfma_f32_16x16x32_bf16(efr[tn][0], x0, acc[tn], 0, 0, 0);
                acc[tn] = __builtin_amdgcn_mfma_f32_16x16x32_bf16(efr[tn][1], x1, acc[tn], 0, 0, 0);
            }
            float best = 3.4e38f; int bk = kbaseLane;
            #pragma unroll
            for (int tn = 0; tn < 4; ++tn) {
                #pragma unroll
                for (int r = 0; r < 4; ++r) {
                    const float Bj = (r == 0) ? Bn[tn].x : (r == 1) ? Bn[tn].y : (r == 2) ? Bn[tn].z : Bn[tn].w;
                    const float d = Bj - 2.0f * acc[tn][r];
                    if (d < best) { best = d; bk = kbaseLane + tn * 16 + r; }
                }
            }
            #pragma unroll
            for (int s = 16; s <= 32; s <<= 1) {
                const float od = __shfl_xor(best, s);
                const int   ok = __shfl_xor(bk, s);
                if (od < best || (od == best && ok < bk)) { best = od; bk = ok; }
            }
            if (q == 0) {
                sdw[v][g * 64 + rt * 16 + cidx] = best;
                skw[v][g * 64 + rt * 16 + cidx] = bk;
            }
        }
    }
    lds_barrier();   // b2: ALL groups' per-wave argmins shared

    // every thread finalizes its own row (= lane) for all 4 groups
    float fdv[4]; int fkv[4];
    #pragma unroll
    for (int g = 0; g < 4; ++g) {
        float fd = sdw[0][g * 64 + lane];
        int   fk = skw[0][g * 64 + lane];
        #pragma unroll
        for (int vv = 1; vv < 8; ++vv) {
            const float dv = sdw[vv][g * 64 + lane];
            const int   kv = skw[vv][g * 64 + lane];
            if (dv < fd) { fd = dv; fk = kv; }
        }
        fdv[g] = fd; fkv[g] = fk;
        if (v == 0) fkL[g][lane] = fk;
    }
    if (v == 0) {
        #pragma unroll
        for (int g = 0; g < 4; ++g) lacc += fdv[g];   // per-row loss = ||x||^2 + fd
    }
    lds_barrier();   // b3: fkL visible

    // ---- phase 3: ALL eq gathers (loads; own row's fk from regs; still no stores) ----
    const int w   = tid & 63;
    const int cq8 = tid >> 6;   // channel octet 0..7
    float4 eqa[4], eqb[4];
    #pragma unroll
    for (int g = 0; g < 4; ++g) {
        const float* ep = emb + (size_t)fkv[g] * 64 + cq8 * 8;
        eqa[g] = *reinterpret_cast<const float4*>(ep);
        eqb[g] = *reinterpret_cast<const float4*>(ep + 4);
    }

    // ---- phase 4: ALL stores (fire-and-forget) ----
    if (v == 0) {
        #pragma unroll
        for (int g = 0; g < 4; ++g) idx[((int)blockIdx.x * 4 + g) * 64 + lane] = fkv[g];
    }
    #pragma unroll
    for (int g = 0; g < 4; ++g) {
        const int gab = (int)blockIdx.x * 4 + g;
        const size_t qBase = OFF_Q + (size_t)(gab >> 6) * 262144 + (size_t)(gab & 63) * 64 + (size_t)w;
        #pragma unroll
        for (int cc = 0; cc < 4; ++cc)
            out[qBase + (size_t)(cq8 * 8 + cc) * 4096] = (cc == 0) ? eqa[g].x : (cc == 1) ? eqa[g].y : (cc == 2) ? eqa[g].z : eqa[g].w;
        #pragma unroll
        for (int cc = 0; cc < 4; ++cc)
            out[qBase + (size_t)(cq8 * 8 + 4 + cc) * 4096] = (cc == 0) ? eqb[g].x : (cc == 1) ? eqb[g].y : (cc == 2) ? eqb[g].z : eqb[g].w;
    }
    #pragma unroll 1
    for (int g = 0; g < 4; ++g) {
        const int gab = (int)blockIdx.x * 4 + g;
        float2* enc2 = reinterpret_cast<float2*>(out + OFF_ENC + (size_t)gab * 32768);
        #pragma unroll 8
        for (int z = 0; z < 32; ++z) {
            const int p = z * 512 + tid;
            const int row = p >> 8;
            const int col2 = p & 255;
            const int k = fkL[g][row];   // LDS broadcast
            float2 val;
            val.x = ((k >> 1) == col2 && (k & 1) == 0) ? 1.0f : 0.0f;
            val.y = ((k >> 1) == col2 && (k & 1) == 1) ? 1.0f : 0.0f;
            enc2[p] = val;
        }
    }

    // loss partial (deterministic, no atomics)
    #pragma unroll
    for (int off = 32; off > 0; off >>= 1) lacc += __shfl_down(lacc, off);
    if (lane == 0) lossW[v] = lacc;
    lds_barrier();
    if (tid == 0) {
        float s = 0.f;
        #pragma unroll
        for (int i = 0; i < 8; ++i) s += lossW[i];
        lossPart[blockIdx.x] = s;
    }
}

// ---- vq_hist: counts via LDS histogram ----
__global__ __launch_bounds__(256) void vq_hist(const int* __restrict__ idx,
                                               unsigned* __restrict__ counts) {
    __shared__ unsigned h[512];
    const int tid = (int)threadIdx.x;
    h[tid] = 0u; h[tid + 256] = 0u;
    __syncthreads();
    const int base = (int)blockIdx.x * 2048;
    #pragma unroll
    for (int i = 0; i < 8; ++i)
        atomicAdd(&h[idx[base + i * 256 + tid]], 1u);
    __syncthreads();
    atomicAdd(&counts[tid], h[tid]);
    atomicAdd(&counts[tid + 256], h[tid + 256]);
}

__global__ __launch_bounds__(512) void vq_fin(const unsigned* __restrict__ counts,
                                              const float* __restrict__ lossPart,
                                              float* __restrict__ out) {
    __shared__ float red[512];
    __shared__ float lr[512];
    int k = threadIdx.x;
    float p = (float)counts[k] * (1.0f / 131072.0f);   // exact: count * 2^-17
    red[k] = p * logf(p + 1e-10f);
    lr[k] = lossPart[k];
    __syncthreads();
    for (int s = 256; s > 0; s >>= 1) {
        if (k < s) { red[k] += red[k + s]; lr[k] += lr[k + s]; }
        __syncthreads();
    }
    if (k == 0) {
        out[OFF_PERP] = expf(-red[0]);
        float mf = lr[0] * (1.0f / 8388608.0f);
        out[0] = mf + 0.25f * mf;   // q_latent + 0.25 * e_latent (identical values)
    }
}

extern "C" void kernel_launch(void* const* d_in, const int* in_sizes, int n_in,
                              void* d_out, int out_size, void* d_ws, size_t ws_size,
                              hipStream_t stream) {
    const float* in  = (const float*)d_in[0];
    // d_in[1] = labels (unused by the reference forward)
    const float* emb = (const float*)d_in[2];
    float* out = (float*)d_out;

    float* Bk        = (float*)d_ws;                      // 512 f32   [0,2048)
    unsigned* counts = (unsigned*)((char*)d_ws + 2048);   // 512 u32   [2048,4096)
    float* lossPart  = (float*)((char*)d_ws + 4096);      // 512 f32   [4096,6144)
    int* idx         = (int*)((char*)d_ws + 8192);        // 131072 i32

    vq_prep<<<1, 512, 0, stream>>>(emb, Bk, counts);
    vq_all<<<512, 512, 0, stream>>>(in, emb, Bk, idx, lossPart, out);
    vq_hist<<<64, 256, 0, stream>>>(idx, counts);
    vq_fin<<<1, 512, 0, stream>>>(counts, lossPart, out);
}